// Round 8
// baseline (105.650 us; speedup 1.0000x reference)
//
#include <hip/hip_runtime.h>
#include <hip/hip_bf16.h>

#define HIDDIM 256
#define NHEADS 8
#define HEADDIM 32
#define SEQ 2048
#define NBATCH 2
#define NTOK (NBATCH * SEQ)
#define RSCALE 0.17677669529663687f  // 1/sqrt(32)
#define LOG2E 1.4426950408889634f
#define NSEG 2
#define SEGLEN (SEQ / NSEG)          // 1024
#define CHUNK 64
#define NCH (SEGLEN / CHUNK)         // 16

typedef __attribute__((ext_vector_type(8))) short bfrag;   // 8 bf16 in 4 VGPRs
typedef __attribute__((ext_vector_type(4))) short s16x4;
typedef __attribute__((ext_vector_type(4))) float f32x4;
typedef __attribute__((ext_vector_type(8))) float f32x8;
typedef __attribute__((ext_vector_type(2))) unsigned u32x2;

static __device__ __forceinline__ short f2bs(float x) {
    __hip_bfloat16 h = __float2bfloat16(x);
    return *reinterpret_cast<short*>(&h);
}
static __device__ __forceinline__ float bs2f(short s) {
    unsigned u = (unsigned)(unsigned short)s << 16;
    return *reinterpret_cast<float*>(&u);
}
static __device__ __forceinline__ unsigned pack2(float a, float b) {
    return (unsigned(f2bs(a)) & 0xffffu) | (unsigned(f2bs(b)) << 16);
}
static __device__ __forceinline__ void gll16(const void* g, void* l) {
    __builtin_amdgcn_global_load_lds(
        (const __attribute__((address_space(1))) void*)g,
        (__attribute__((address_space(3))) void*)l, 16, 0, 0);
}

// ---------------------------------------------------------------------------
// Weight prep (f32 -> bf16, 4 elems/thread, 256 blocks) + mask bitfield.
// mb[word] bit i = (mask[word*32+i] != 0). 128 words total.
// ---------------------------------------------------------------------------
__global__ __launch_bounds__(256) void prep_kernel(
    const float* __restrict__ Wq, const float* __restrict__ Wk,
    const float* __restrict__ Wv, const float* __restrict__ Wfc,
    const int* __restrict__ mask,
    short* __restrict__ Whi, unsigned* __restrict__ mb)
{
    const int tid = threadIdx.x;
    const int idx = (blockIdx.x * 256 + tid) * 4;
    const int w = blockIdx.y;
    const float* src = (w == 0) ? Wq : (w == 1) ? Wk : (w == 2) ? Wv : Wfc;
    const f32x4 v = *(const f32x4*)(src + idx);
    s16x4 o;
    #pragma unroll
    for (int j = 0; j < 4; ++j) o[j] = f2bs(v[j]);
    *(s16x4*)(Whi + w * 65536 + idx) = o;
    if (w == 0) {
        const int gw = blockIdx.x * 4 + (tid >> 6);   // global wave id
        if (gw < NTOK / 64) {                          // wave-uniform
            const int lane = tid & 63;
            const unsigned long long bal = __ballot(mask[gw * 64 + lane] != 0);
            if (lane == 0) {
                mb[gw * 2]     = (unsigned)bal;
                mb[gw * 2 + 1] = (unsigned)(bal >> 32);
            }
        }
    }
}

// ---------------------------------------------------------------------------
// QKV projection (bf16 MFMA). Q scaled by log2e/sqrt(HD) (exp2 fold).
// grid (NTOK/16, 3) = 768 blocks (3/CU): block = 16 rows x 4 col-waves
// (64 cols each). All 4 waves read the same input rows (L1 dedup) so each
// f32 row is fetched from HBM once. V stored transposed: Vt[b][h][d][s].
// ---------------------------------------------------------------------------
__global__ __launch_bounds__(256) void qkv_kernel(
    const float* __restrict__ qin, const float* __restrict__ kin,
    const float* __restrict__ vin,
    const float* __restrict__ bq, const float* __restrict__ bk,
    const float* __restrict__ bv,
    const short* __restrict__ Whi,
    short* __restrict__ Qw, short* __restrict__ Kw, short* __restrict__ Vt)
{
    const int lane = threadIdx.x & 63;
    const int wid  = threadIdx.x >> 6;
    const int lr = lane & 15, lg = lane >> 4;
    const int which = blockIdx.y;

    const float* in   = which == 0 ? qin : (which == 1 ? kin : vin);
    const float* bias = which == 0 ? bq  : (which == 1 ? bk  : bv);
    const short* W = Whi + which * 65536;

    const int row0 = blockIdx.x * 16;
    const int col0 = wid * 64;

    f32x4 acc[4] = {};
    const float* arow = in + (size_t)(row0 + lr) * HIDDIM + lg * 8;
    #pragma unroll
    for (int k0 = 0; k0 < HIDDIM; k0 += 32) {
        const f32x8 af = *(const f32x8*)(arow + k0);
        bfrag a;
        #pragma unroll
        for (int j = 0; j < 8; ++j) a[j] = f2bs(af[j]);
        #pragma unroll
        for (int nt = 0; nt < 4; ++nt) {
            const bfrag bf = *(const bfrag*)(W + (size_t)(col0 + nt * 16 + lr) * HIDDIM + k0 + lg * 8);
            acc[nt] = __builtin_amdgcn_mfma_f32_16x16x32_bf16(a, bf, acc[nt], 0, 0, 0);
        }
    }

    #pragma unroll
    for (int nt = 0; nt < 4; ++nt) {
        const int col = col0 + nt * 16 + lr;
        const float bval = bias[col];
        #pragma unroll
        for (int r = 0; r < 4; ++r) {
            const int row = row0 + lg * 4 + r;
            float v = acc[nt][r] + bval;
            if (which == 0) {
                Qw[(size_t)row * HIDDIM + col] = f2bs(v * (RSCALE * LOG2E));
            } else if (which == 1) {
                Kw[(size_t)row * HIDDIM + col] = f2bs(v);
            } else {
                const int h = col >> 5, d = col & 31;
                const int bb = row >> 11, ss = row & (SEQ - 1);
                Vt[(((size_t)(bb * NHEADS + h) * HEADDIM + d) << 11) + ss] = f2bs(v);
            }
        }
    }
}

// ---------------------------------------------------------------------------
// Flash attention, split-K, swapped operands, fixed-max softmax (exp2).
// grid 1024 blocks (XCD-chunk-swizzled), block 256 (4 waves).
// Triple-buffered K/V via global_load_lds issued 2 chunks ahead; pos
// reg-prefetched 2 chunks ahead; mask from SGPR bitfield (pre-rotated).
// SPLIT VMCNT: drain gll(t) only (vmcnt 10) before the barrier (LDS K
// needed at QK); drain pos(t) (vmcnt 12) after QK and after issuing chunk
// t+2's gll+pos -> pos gets ~QK-duration extra latency cover and the
// barrier drain is less bursty. Queue invariant: 12 outstanding at loop
// top = [gll(t)2, pos(t)4, gll(t+1)2, pos(t+1)4].
// PER-BLOCK K-PHASE ROTATION: chunks processed in order (t+phase)%16 so
// co-resident blocks touch different 256B pos column offsets.
// s_setprio(1) wraps the QK->softmax->PV compute region (T5).
// EPILOGUE: per-segment normalization in-register; writes bf16 partial X.
// ---------------------------------------------------------------------------
__global__ __launch_bounds__(256, 4) void attn_kernel(
    const short* __restrict__ Q, const short* __restrict__ K,
    const short* __restrict__ Vt,
    const float* __restrict__ pos,
    const unsigned* __restrict__ mbits,
    short* __restrict__ Xp, float* __restrict__ Sp)
{
    const int lane = threadIdx.x & 63;
    const int wid  = threadIdx.x >> 6;
    const int lr = lane & 15, lg = lane >> 4;

    // XCD-chunked bijective swizzle: 1024 blocks, 8 XCDs, 128 per XCD.
    const int lb = blockIdx.x + 32 * (blockIdx.y + 16 * blockIdx.z);
    const int work = ((lb & 7) << 7) | (lb >> 3);
    const int xb = work & 31;            // q-block group
    const int bh = (work >> 5) & 15;     // batch*head
    const int zb = work >> 9;            // segment
    const int b = bh >> 3, h = bh & 7;
    const int phase = work & 15;         // k-chunk rotation

    const int qblk = xb * 4 + wid;       // 0..127
    const int q0 = qblk * 16;
    const int c0 = zb * SEGLEN;

    __shared__ short KVb[3][8][512];   // [buf][slot 0-3:K tiles, 4-7:V frags]
    __shared__ short Pl[4][16][68];    // wave-private P transpose tile

    // segment mask bits -> SGPRs, pre-rotated so in-loop index is static
    unsigned mw[32];
    {
        const unsigned* mwp = mbits + b * 64 + (c0 >> 5);
        #pragma unroll
        for (int j = 0; j < 32; ++j)
            mw[j] = __builtin_amdgcn_readfirstlane(mwp[(j + 2 * phase) & 31]);
    }

    const bfrag qf = *(const bfrag*)(Q + (size_t)(b * SEQ + q0 + lr) * HIDDIM + h * HEADDIM + lg * 8);

    // staging sources for this wave's slots
    const short* Kg = K + (size_t)b * SEQ * HIDDIM + h * HEADDIM + lg * 8;
    const int vtile = wid >> 1, vsub = wid & 1;
    const short* Vg = Vt + ((size_t)(bh * HEADDIM + vtile * 16 + lr) << 11) + vsub * 32 + lg * 8;

    const float* posb = pos + (size_t)(bh * SEQ + q0 + lr) * SEQ;

    f32x4 posr[3][4];
    f32x4 o0 = {}, o1 = {};
    float s_acc = 0.0f;

    // prologue: queue order = [gll0 x2, pos0 x4, gll1 x2, pos1 x4] (rotated)
    {
        const int ca = c0 + phase * CHUNK;
        const int cb2 = c0 + (((1 + phase) & 15) * CHUNK);
        gll16(Kg + (size_t)(ca + wid * 16 + lr) * HIDDIM, &KVb[0][wid][lane * 8]);
        gll16(Vg + ca, &KVb[0][4 + wid][lane * 8]);
        __builtin_amdgcn_sched_barrier(0);
        #pragma unroll
        for (int tt = 0; tt < 4; ++tt)
            posr[0][tt] = *(const f32x4*)(posb + ca + tt * 16 + lg * 4);
        __builtin_amdgcn_sched_barrier(0);
        gll16(Kg + (size_t)(cb2 + wid * 16 + lr) * HIDDIM, &KVb[1][wid][lane * 8]);
        gll16(Vg + cb2, &KVb[1][4 + wid][lane * 8]);
        __builtin_amdgcn_sched_barrier(0);
        #pragma unroll
        for (int tt = 0; tt < 4; ++tt)
            posr[1][tt] = *(const f32x4*)(posb + cb2 + tt * 16 + lg * 4);
        __builtin_amdgcn_sched_barrier(0);
    }

    #pragma unroll
    for (int t = 0; t < NCH; ++t) {
        const int cur = t % 3;

        // drain gll(t) (oldest 2) only -- K/V LDS needed at the barrier
        if (t < NCH - 1) { asm volatile("s_waitcnt vmcnt(10)" ::: "memory"); }
        else             { asm volatile("s_waitcnt vmcnt(4)" ::: "memory"); }
        __builtin_amdgcn_sched_barrier(0);
        __builtin_amdgcn_s_barrier();
        __builtin_amdgcn_sched_barrier(0);

        // stage chunk t+2 (gll into buf[(t+2)%3] + pos into posr[(t+2)%3])
        if (t + 2 < NCH) {
            const int cn = c0 + (((t + 2 + phase) & 15) * CHUNK);
            gll16(Kg + (size_t)(cn + wid * 16 + lr) * HIDDIM, &KVb[(t + 2) % 3][wid][lane * 8]);
            gll16(Vg + cn, &KVb[(t + 2) % 3][4 + wid][lane * 8]);
            #pragma unroll
            for (int tt = 0; tt < 4; ++tt)
                posr[(t + 2) % 3][tt] = *(const f32x4*)(posb + cn + tt * 16 + lg * 4);
        }
        __builtin_amdgcn_sched_barrier(0);
        __builtin_amdgcn_s_setprio(1);

        // K frags from LDS + QK^T (swapped: E[k][q])
        f32x4 e[4];
        #pragma unroll
        for (int tt = 0; tt < 4; ++tt) {
            const bfrag kf = *(const bfrag*)&KVb[cur][tt][lane * 8];
            const f32x4 z = {};
            e[tt] = __builtin_amdgcn_mfma_f32_16x16x32_bf16(kf, qf, z, 0, 0, 0);
        }
        __builtin_amdgcn_sched_barrier(0);

        // drain pos(t) (oldest 4 of the remaining queue)
        if (t + 2 < NCH)      { asm volatile("s_waitcnt vmcnt(12)" ::: "memory"); }
        else if (t == NCH - 2){ asm volatile("s_waitcnt vmcnt(6)"  ::: "memory"); }
        else                  { asm volatile("s_waitcnt vmcnt(0)"  ::: "memory"); }
        __builtin_amdgcn_sched_barrier(0);

        // p = maskbit ? exp2(e + pos*log2e) : 0   (fixed-max softmax)
        #pragma unroll
        for (int tt = 0; tt < 4; ++tt) {
            const unsigned shifted = mw[t * 2 + (tt >> 1)] >> (((tt & 1) << 4) + (lg << 2));
            float p[4];
            #pragma unroll
            for (int r = 0; r < 4; ++r) {
                const float ev = exp2f(fmaf(posr[cur][tt][r], LOG2E, e[tt][r]));
                p[r] = (shifted & (1u << r)) ? ev : 0.0f;
                s_acc += p[r];
            }
            u32x2 w = { pack2(p[0], p[1]), pack2(p[2], p[3]) };
            *(u32x2*)&Pl[wid][lr][tt * 16 + lg * 4] = w;   // P[q=lr][k_local]
        }

        // PV: O^T[d][q] += V^T-frag x P-frag
        #pragma unroll
        for (int s = 0; s < 2; ++s) {
            const bfrag pf  = *(const bfrag*)&Pl[wid][lr][s * 32 + lg * 8];
            const bfrag vf0 = *(const bfrag*)&KVb[cur][4 + 0 + s][lane * 8];
            const bfrag vf1 = *(const bfrag*)&KVb[cur][4 + 2 + s][lane * 8];
            o0 = __builtin_amdgcn_mfma_f32_16x16x32_bf16(vf0, pf, o0, 0, 0, 0);
            o1 = __builtin_amdgcn_mfma_f32_16x16x32_bf16(vf1, pf, o1, 0, 0, 0);
        }
        __builtin_amdgcn_s_setprio(0);
        // no trailing barrier: next iteration's top barrier syncs buffers
    }

    // denominator for q=lr lives across lanes lr, lr+16, lr+32, lr+48
    s_acc += __shfl_xor(s_acc, 16, 64);
    s_acc += __shfl_xor(s_acc, 32, 64);
    const float inv = 1.0f / s_acc;

    // per-segment normalize, pack bf16, transpose via Pl (wave-private, all
    // main-loop uses complete), write partial X for this segment
    {
        u32x2 w0 = { pack2(o0[0] * inv, o0[1] * inv), pack2(o0[2] * inv, o0[3] * inv) };
        u32x2 w1 = { pack2(o1[0] * inv, o1[1] * inv), pack2(o1[2] * inv, o1[3] * inv) };
        *(u32x2*)&Pl[wid][lr][lg * 4]      = w0;   // (q=lr, d=lg*4+r)
        *(u32x2*)&Pl[wid][lr][16 + lg * 4] = w1;   // (q=lr, d=16+lg*4+r)
        const bfrag xr = *(const bfrag*)&Pl[wid][lr][lg * 8];
        *(bfrag*)(Xp + ((size_t)zb * NTOK + b * SEQ + q0 + lr) * HIDDIM + h * HEADDIM + lg * 8) = xr;
    }
    if (lg == 0)
        Sp[((size_t)(zb * 16 + bh) * 128 + qblk) * 16 + lr] = s_acc;
}

// ---------------------------------------------------------------------------
// Fused combine + output projection: out = X @ Wfc^T + bfc where
// X = w0*Xp[seg0] + w1*Xp[seg1], w_i = s_i/(s0+s1) (per head, per row).
// Xp is bf16 in [b*S+q][hid] layout so the A-fragment is a direct bf16x8
// load per segment. grid (256, 2) = 512 blocks (2/CU).
// ---------------------------------------------------------------------------
__global__ __launch_bounds__(256) void fc_kernel(
    const short* __restrict__ Xp, const float* __restrict__ Sp,
    const short* __restrict__ Whi,   // Wfc at slot 3
    const float* __restrict__ bias,
    float* __restrict__ out)
{
    const int lane = threadIdx.x & 63;
    const int wid  = threadIdx.x >> 6;
    const int lr = lane & 15, lg = lane >> 4;

    const int row0 = blockIdx.x * 16;
    const int col0 = blockIdx.y * 128 + wid * 32;
    const short* W = Whi + 3 * 65536;

    const int qb = blockIdx.x & 127;     // qblk
    const int b  = blockIdx.x >> 7;      // batch

    // per-head combine weights for this thread's row (q = lr)
    float wA[NHEADS], wB[NHEADS];
    #pragma unroll
    for (int h = 0; h < NHEADS; ++h) {
        const float s0 = Sp[((size_t)(b * NHEADS + h) * 128 + qb) * 16 + lr];
        const float s1 = Sp[((size_t)(16 + b * NHEADS + h) * 128 + qb) * 16 + lr];
        const float invt = 1.0f / (s0 + s1);
        wA[h] = s0 * invt;
        wB[h] = s1 * invt;
    }

    const size_t rowa = (size_t)(row0 + lr) * HIDDIM;
    f32x4 acc[2] = {};
    #pragma unroll
    for (int k0 = 0; k0 < HIDDIM; k0 += 32) {
        const int h = k0 >> 5;           // head for this k-step (static)
        const bfrag xa = *(const bfrag*)(Xp + rowa + k0 + lg * 8);
        const bfrag xb = *(const bfrag*)(Xp + (size_t)NTOK * HIDDIM + rowa + k0 + lg * 8);
        bfrag a;
        #pragma unroll
        for (int j = 0; j < 8; ++j)
            a[j] = f2bs(bs2f(xa[j]) * wA[h] + bs2f(xb[j]) * wB[h]);
        #pragma unroll
        for (int nt = 0; nt < 2; ++nt) {
            const bfrag bf = *(const bfrag*)(W + (size_t)(col0 + nt * 16 + lr) * HIDDIM + k0 + lg * 8);
            acc[nt] = __builtin_amdgcn_mfma_f32_16x16x32_bf16(a, bf, acc[nt], 0, 0, 0);
        }
    }

    #pragma unroll
    for (int nt = 0; nt < 2; ++nt) {
        const int col = col0 + nt * 16 + lr;
        const float bval = bias[col];
        #pragma unroll
        for (int r = 0; r < 4; ++r) {
            const int row = row0 + lg * 4 + r;
            out[(size_t)row * HIDDIM + col] = acc[nt][r] + bval;
        }
    }
}

extern "C" void kernel_launch(void* const* d_in, const int* in_sizes, int n_in,
                              void* d_out, int out_size, void* d_ws, size_t ws_size,
                              hipStream_t stream)
{
    (void)in_sizes; (void)n_in; (void)out_size; (void)ws_size;

    const float* qin  = (const float*)d_in[0];
    const float* kin  = (const float*)d_in[1];
    const float* vin  = (const float*)d_in[2];
    const float* pos  = (const float*)d_in[3];
    const int*   mask = (const int*)d_in[4];
    const float* Wq   = (const float*)d_in[5];
    const float* bq   = (const float*)d_in[6];
    const float* Wk   = (const float*)d_in[7];
    const float* bk   = (const float*)d_in[8];
    const float* Wv   = (const float*)d_in[9];
    const float* bv   = (const float*)d_in[10];
    const float* Wfc  = (const float*)d_in[11];
    const float* bfc  = (const float*)d_in[12];
    float* out = (float*)d_out;

    short* ws  = (short*)d_ws;
    short* Whi = ws;                                  // 4*65536 shorts
    short* Qw  = Whi + 4 * 65536;
    short* Kw  = Qw + (size_t)NTOK * HIDDIM;
    short* Vt  = Kw + (size_t)NTOK * HIDDIM;
    short* Xp  = Vt + (size_t)NTOK * HIDDIM;              // NSEG*NTOK*HIDDIM bf16
    float* Sp  = (float*)(Xp + (size_t)NSEG * NTOK * HIDDIM);  // NSEG*16*128*16 f32
    unsigned* Mb = (unsigned*)(Sp + (size_t)NSEG * 16 * 128 * 16);  // 128 u32

    prep_kernel<<<dim3(64, 4), 256, 0, stream>>>(Wq, Wk, Wv, Wfc, mask, Whi, Mb);
    qkv_kernel<<<dim3(NTOK / 16, 3), 256, 0, stream>>>(
        qin, kin, vin, bq, bk, bv, Whi, Qw, Kw, Vt);
    attn_kernel<<<dim3(SEQ / 64, NBATCH * NHEADS, NSEG), 256, 0, stream>>>(
        Qw, Kw, Vt, pos, Mb, Xp, Sp);
    fc_kernel<<<dim3(NTOK / 16, 2), 256, 0, stream>>>(
        Xp, Sp, Whi, bfc, out);
}

// Round 9
// 97.508 us; speedup vs baseline: 1.0835x; 1.0835x over previous
//
#include <hip/hip_runtime.h>
#include <hip/hip_bf16.h>

#define HIDDIM 256
#define NHEADS 8
#define HEADDIM 32
#define SEQ 2048
#define NBATCH 2
#define NTOK (NBATCH * SEQ)
#define RSCALE 0.17677669529663687f  // 1/sqrt(32)
#define LOG2E 1.4426950408889634f
#define NSEG 2
#define SEGLEN (SEQ / NSEG)          // 1024
#define CHUNK 64
#define NCH (SEGLEN / CHUNK)         // 16

typedef __attribute__((ext_vector_type(8))) short bfrag;   // 8 bf16 in 4 VGPRs
typedef __attribute__((ext_vector_type(4))) float f32x4;
typedef __attribute__((ext_vector_type(8))) float f32x8;
typedef __attribute__((ext_vector_type(2))) unsigned u32x2;

static __device__ __forceinline__ short f2bs(float x) {
    __hip_bfloat16 h = __float2bfloat16(x);
    return *reinterpret_cast<short*>(&h);
}
static __device__ __forceinline__ float bs2f(short s) {
    unsigned u = (unsigned)(unsigned short)s << 16;
    return *reinterpret_cast<float*>(&u);
}
static __device__ __forceinline__ unsigned pack2(float a, float b) {
    return (unsigned(f2bs(a)) & 0xffffu) | (unsigned(f2bs(b)) << 16);
}
static __device__ __forceinline__ void gll16(const void* g, void* l) {
    __builtin_amdgcn_global_load_lds(
        (const __attribute__((address_space(1))) void*)g,
        (__attribute__((address_space(3))) void*)l, 16, 0, 0);
}

// ---------------------------------------------------------------------------
// Weight prep (f32 -> bf16 for all 4 weight matrices) + mask bitfield fused.
// mb[word] bit i = (mask[word*32+i] != 0). 128 words total.
// ---------------------------------------------------------------------------
__global__ __launch_bounds__(256) void prep_kernel(
    const float* __restrict__ Wq, const float* __restrict__ Wk,
    const float* __restrict__ Wv, const float* __restrict__ Wfc,
    const int* __restrict__ mask,
    short* __restrict__ Whi, unsigned* __restrict__ mb)
{
    const int idx = blockIdx.x * 256 + threadIdx.x;
    const int w = blockIdx.y;
    const float* src = (w == 0) ? Wq : (w == 1) ? Wk : (w == 2) ? Wv : Wfc;
    Whi[w * 65536 + idx] = f2bs(src[idx]);
    if (w == 0 && idx < NTOK) {   // wave-uniform condition (NTOK % 64 == 0)
        const unsigned long long bal = __ballot(mask[idx] != 0);
        if ((threadIdx.x & 63) == 0) {
            const int wd = idx >> 5;
            mb[wd]     = (unsigned)bal;
            mb[wd + 1] = (unsigned)(bal >> 32);
        }
    }
}

// ---------------------------------------------------------------------------
// QKV projection (bf16 MFMA). Q scaled by log2e/sqrt(HD) (exp2 fold).
// grid (NTOK/16, 3) = 768 blocks (3/CU): block = 16 rows x 4 col-waves
// (64 cols each). All 4 waves read the same input rows (L1 dedup) so each
// f32 row is fetched from HBM once. V stored transposed: Vt[b][h][d][s].
// ---------------------------------------------------------------------------
__global__ __launch_bounds__(256) void qkv_kernel(
    const float* __restrict__ qin, const float* __restrict__ kin,
    const float* __restrict__ vin,
    const float* __restrict__ bq, const float* __restrict__ bk,
    const float* __restrict__ bv,
    const short* __restrict__ Whi,
    short* __restrict__ Qw, short* __restrict__ Kw, short* __restrict__ Vt)
{
    const int lane = threadIdx.x & 63;
    const int wid  = threadIdx.x >> 6;
    const int lr = lane & 15, lg = lane >> 4;
    const int which = blockIdx.y;

    const float* in   = which == 0 ? qin : (which == 1 ? kin : vin);
    const float* bias = which == 0 ? bq  : (which == 1 ? bk  : bv);
    const short* W = Whi + which * 65536;

    const int row0 = blockIdx.x * 16;
    const int col0 = wid * 64;

    f32x4 acc[4] = {};
    const float* arow = in + (size_t)(row0 + lr) * HIDDIM + lg * 8;
    #pragma unroll
    for (int k0 = 0; k0 < HIDDIM; k0 += 32) {
        const f32x8 af = *(const f32x8*)(arow + k0);
        bfrag a;
        #pragma unroll
        for (int j = 0; j < 8; ++j) a[j] = f2bs(af[j]);
        #pragma unroll
        for (int nt = 0; nt < 4; ++nt) {
            const bfrag bf = *(const bfrag*)(W + (size_t)(col0 + nt * 16 + lr) * HIDDIM + k0 + lg * 8);
            acc[nt] = __builtin_amdgcn_mfma_f32_16x16x32_bf16(a, bf, acc[nt], 0, 0, 0);
        }
    }

    #pragma unroll
    for (int nt = 0; nt < 4; ++nt) {
        const int col = col0 + nt * 16 + lr;
        const float bval = bias[col];
        #pragma unroll
        for (int r = 0; r < 4; ++r) {
            const int row = row0 + lg * 4 + r;
            float v = acc[nt][r] + bval;
            if (which == 0) {
                Qw[(size_t)row * HIDDIM + col] = f2bs(v * (RSCALE * LOG2E));
            } else if (which == 1) {
                Kw[(size_t)row * HIDDIM + col] = f2bs(v);
            } else {
                const int h = col >> 5, d = col & 31;
                const int bb = row >> 11, ss = row & (SEQ - 1);
                Vt[(((size_t)(bb * NHEADS + h) * HEADDIM + d) << 11) + ss] = f2bs(v);
            }
        }
    }
}

// ---------------------------------------------------------------------------
// Flash attention, split-K, swapped operands, fixed-max softmax (exp2).
// grid 1024 blocks (XCD-chunk-swizzled), block 256 (4 waves).
// Triple-buffered K/V via global_load_lds issued 2 chunks ahead; pos
// reg-prefetched 2 chunks ahead; mask from SGPR bitfield (pre-rotated).
// PER-BLOCK K-PHASE ROTATION: block processes chunks in order
// (t+phase)%16, phase=work&15, so co-resident blocks touch different
// 256B pos column offsets -> spread across memory channels.
// s_setprio(1) wraps the QK->softmax->PV compute region (T5).
// EPILOGUE: per-segment normalization in-register; writes bf16 partial X
// (Xp[zb] in [b*S+q][hid] layout, via the wave-private Pl transpose tile)
// plus the f32 denominator Sp.
// ---------------------------------------------------------------------------
__global__ __launch_bounds__(256, 4) void attn_kernel(
    const short* __restrict__ Q, const short* __restrict__ K,
    const short* __restrict__ Vt,
    const float* __restrict__ pos,
    const unsigned* __restrict__ mbits,
    short* __restrict__ Xp, float* __restrict__ Sp)
{
    const int lane = threadIdx.x & 63;
    const int wid  = threadIdx.x >> 6;
    const int lr = lane & 15, lg = lane >> 4;

    // XCD-chunked bijective swizzle: 1024 blocks, 8 XCDs, 128 per XCD.
    const int lb = blockIdx.x + 32 * (blockIdx.y + 16 * blockIdx.z);
    const int work = ((lb & 7) << 7) | (lb >> 3);
    const int xb = work & 31;            // q-block group
    const int bh = (work >> 5) & 15;     // batch*head
    const int zb = work >> 9;            // segment
    const int b = bh >> 3, h = bh & 7;
    const int phase = work & 15;         // k-chunk rotation

    const int qblk = xb * 4 + wid;       // 0..127
    const int q0 = qblk * 16;
    const int c0 = zb * SEGLEN;

    __shared__ short KVb[3][8][512];   // [buf][slot 0-3:K tiles, 4-7:V frags]
    __shared__ short Pl[4][16][68];    // wave-private P transpose tile

    // segment mask bits -> SGPRs, pre-rotated so in-loop index is static
    unsigned mw[32];
    {
        const unsigned* mwp = mbits + b * 64 + (c0 >> 5);
        #pragma unroll
        for (int j = 0; j < 32; ++j)
            mw[j] = __builtin_amdgcn_readfirstlane(mwp[(j + 2 * phase) & 31]);
    }

    const bfrag qf = *(const bfrag*)(Q + (size_t)(b * SEQ + q0 + lr) * HIDDIM + h * HEADDIM + lg * 8);

    // staging sources for this wave's slots
    const short* Kg = K + (size_t)b * SEQ * HIDDIM + h * HEADDIM + lg * 8;
    const int vtile = wid >> 1, vsub = wid & 1;
    const short* Vg = Vt + ((size_t)(bh * HEADDIM + vtile * 16 + lr) << 11) + vsub * 32 + lg * 8;

    const float* posb = pos + (size_t)(bh * SEQ + q0 + lr) * SEQ;

    f32x4 posr[3][4];
    f32x4 o0 = {}, o1 = {};
    float s_acc = 0.0f;

    // prologue: queue order = [gll0 x2, pos0 x4, gll1 x2, pos1 x4] (rotated)
    {
        const int ca = c0 + phase * CHUNK;
        const int cb2 = c0 + (((1 + phase) & 15) * CHUNK);
        gll16(Kg + (size_t)(ca + wid * 16 + lr) * HIDDIM, &KVb[0][wid][lane * 8]);
        gll16(Vg + ca, &KVb[0][4 + wid][lane * 8]);
        __builtin_amdgcn_sched_barrier(0);
        #pragma unroll
        for (int tt = 0; tt < 4; ++tt)
            posr[0][tt] = *(const f32x4*)(posb + ca + tt * 16 + lg * 4);
        __builtin_amdgcn_sched_barrier(0);
        gll16(Kg + (size_t)(cb2 + wid * 16 + lr) * HIDDIM, &KVb[1][wid][lane * 8]);
        gll16(Vg + cb2, &KVb[1][4 + wid][lane * 8]);
        __builtin_amdgcn_sched_barrier(0);
        #pragma unroll
        for (int tt = 0; tt < 4; ++tt)
            posr[1][tt] = *(const f32x4*)(posb + cb2 + tt * 16 + lg * 4);
        __builtin_amdgcn_sched_barrier(0);
    }

    #pragma unroll
    for (int t = 0; t < NCH; ++t) {
        const int cur = t % 3;

        // chunk t (gll+pos) done; [gll(t+1)x2, pos(t+1)x4] stay in flight
        if (t < NCH - 1) { asm volatile("s_waitcnt vmcnt(6)" ::: "memory"); }
        else             { asm volatile("s_waitcnt vmcnt(0)" ::: "memory"); }
        __builtin_amdgcn_sched_barrier(0);
        __builtin_amdgcn_s_barrier();
        __builtin_amdgcn_sched_barrier(0);

        // stage chunk t+2 into buf[(t+2)%3] (chunk t-1's buffer, now free)
        if (t + 2 < NCH) {
            const int cn = c0 + (((t + 2 + phase) & 15) * CHUNK);
            gll16(Kg + (size_t)(cn + wid * 16 + lr) * HIDDIM, &KVb[(t + 2) % 3][wid][lane * 8]);
            gll16(Vg + cn, &KVb[(t + 2) % 3][4 + wid][lane * 8]);
        }
        __builtin_amdgcn_sched_barrier(0);
        __builtin_amdgcn_s_setprio(1);

        // K frags from LDS + QK^T (swapped: E[k][q])
        f32x4 e[4];
        #pragma unroll
        for (int tt = 0; tt < 4; ++tt) {
            const bfrag kf = *(const bfrag*)&KVb[cur][tt][lane * 8];
            const f32x4 z = {};
            e[tt] = __builtin_amdgcn_mfma_f32_16x16x32_bf16(kf, qf, z, 0, 0, 0);
        }

        // prefetch pos for chunk t+2
        if (t + 2 < NCH) {
            const int cn = c0 + (((t + 2 + phase) & 15) * CHUNK);
            #pragma unroll
            for (int tt = 0; tt < 4; ++tt)
                posr[(t + 2) % 3][tt] = *(const f32x4*)(posb + cn + tt * 16 + lg * 4);
        }
        __builtin_amdgcn_sched_barrier(0);

        // p = maskbit ? exp2(e + pos*log2e) : 0   (fixed-max softmax)
        #pragma unroll
        for (int tt = 0; tt < 4; ++tt) {
            const unsigned shifted = mw[t * 2 + (tt >> 1)] >> (((tt & 1) << 4) + (lg << 2));
            float p[4];
            #pragma unroll
            for (int r = 0; r < 4; ++r) {
                const float ev = exp2f(fmaf(posr[cur][tt][r], LOG2E, e[tt][r]));
                p[r] = (shifted & (1u << r)) ? ev : 0.0f;
                s_acc += p[r];
            }
            u32x2 w = { pack2(p[0], p[1]), pack2(p[2], p[3]) };
            *(u32x2*)&Pl[wid][lr][tt * 16 + lg * 4] = w;   // P[q=lr][k_local]
        }

        // PV: O^T[d][q] += V^T-frag x P-frag
        #pragma unroll
        for (int s = 0; s < 2; ++s) {
            const bfrag pf  = *(const bfrag*)&Pl[wid][lr][s * 32 + lg * 8];
            const bfrag vf0 = *(const bfrag*)&KVb[cur][4 + 0 + s][lane * 8];
            const bfrag vf1 = *(const bfrag*)&KVb[cur][4 + 2 + s][lane * 8];
            o0 = __builtin_amdgcn_mfma_f32_16x16x32_bf16(vf0, pf, o0, 0, 0, 0);
            o1 = __builtin_amdgcn_mfma_f32_16x16x32_bf16(vf1, pf, o1, 0, 0, 0);
        }
        __builtin_amdgcn_s_setprio(0);
        // no trailing barrier: next iteration's top barrier syncs buffers
    }

    // denominator for q=lr lives across lanes lr, lr+16, lr+32, lr+48
    s_acc += __shfl_xor(s_acc, 16, 64);
    s_acc += __shfl_xor(s_acc, 32, 64);
    const float inv = 1.0f / s_acc;

    // per-segment normalize, pack bf16, transpose via Pl (wave-private, all
    // main-loop uses complete), write partial X for this segment
    {
        u32x2 w0 = { pack2(o0[0] * inv, o0[1] * inv), pack2(o0[2] * inv, o0[3] * inv) };
        u32x2 w1 = { pack2(o1[0] * inv, o1[1] * inv), pack2(o1[2] * inv, o1[3] * inv) };
        *(u32x2*)&Pl[wid][lr][lg * 4]      = w0;   // (q=lr, d=lg*4+r)
        *(u32x2*)&Pl[wid][lr][16 + lg * 4] = w1;   // (q=lr, d=16+lg*4+r)
        const bfrag xr = *(const bfrag*)&Pl[wid][lr][lg * 8];
        *(bfrag*)(Xp + ((size_t)zb * NTOK + b * SEQ + q0 + lr) * HIDDIM + h * HEADDIM + lg * 8) = xr;
    }
    if (lg == 0)
        Sp[((size_t)(zb * 16 + bh) * 128 + qblk) * 16 + lr] = s_acc;
}

// ---------------------------------------------------------------------------
// Fused combine + output projection: out = X @ Wfc^T + bfc where
// X = w0*Xp[seg0] + w1*Xp[seg1], w_i = s_i/(s0+s1) (per head, per row).
// Xp is bf16 in [b*S+q][hid] layout so the A-fragment is a direct bf16x8
// load per segment. grid (256, 2) = 512 blocks (2/CU).
// ---------------------------------------------------------------------------
__global__ __launch_bounds__(256) void fc_kernel(
    const short* __restrict__ Xp, const float* __restrict__ Sp,
    const short* __restrict__ Whi,   // Wfc at slot 3
    const float* __restrict__ bias,
    float* __restrict__ out)
{
    const int lane = threadIdx.x & 63;
    const int wid  = threadIdx.x >> 6;
    const int lr = lane & 15, lg = lane >> 4;

    const int row0 = blockIdx.x * 16;
    const int col0 = blockIdx.y * 128 + wid * 32;
    const short* W = Whi + 3 * 65536;

    const int qb = blockIdx.x & 127;     // qblk
    const int b  = blockIdx.x >> 7;      // batch

    // per-head combine weights for this thread's row (q = lr)
    float wA[NHEADS], wB[NHEADS];
    #pragma unroll
    for (int h = 0; h < NHEADS; ++h) {
        const float s0 = Sp[((size_t)(b * NHEADS + h) * 128 + qb) * 16 + lr];
        const float s1 = Sp[((size_t)(16 + b * NHEADS + h) * 128 + qb) * 16 + lr];
        const float invt = 1.0f / (s0 + s1);
        wA[h] = s0 * invt;
        wB[h] = s1 * invt;
    }

    const size_t rowa = (size_t)(row0 + lr) * HIDDIM;
    f32x4 acc[2] = {};
    #pragma unroll
    for (int k0 = 0; k0 < HIDDIM; k0 += 32) {
        const int h = k0 >> 5;           // head for this k-step (static)
        const bfrag xa = *(const bfrag*)(Xp + rowa + k0 + lg * 8);
        const bfrag xb = *(const bfrag*)(Xp + (size_t)NTOK * HIDDIM + rowa + k0 + lg * 8);
        bfrag a;
        #pragma unroll
        for (int j = 0; j < 8; ++j)
            a[j] = f2bs(bs2f(xa[j]) * wA[h] + bs2f(xb[j]) * wB[h]);
        #pragma unroll
        for (int nt = 0; nt < 2; ++nt) {
            const bfrag bf = *(const bfrag*)(W + (size_t)(col0 + nt * 16 + lr) * HIDDIM + k0 + lg * 8);
            acc[nt] = __builtin_amdgcn_mfma_f32_16x16x32_bf16(a, bf, acc[nt], 0, 0, 0);
        }
    }

    #pragma unroll
    for (int nt = 0; nt < 2; ++nt) {
        const int col = col0 + nt * 16 + lr;
        const float bval = bias[col];
        #pragma unroll
        for (int r = 0; r < 4; ++r) {
            const int row = row0 + lg * 4 + r;
            out[(size_t)row * HIDDIM + col] = acc[nt][r] + bval;
        }
    }
}

extern "C" void kernel_launch(void* const* d_in, const int* in_sizes, int n_in,
                              void* d_out, int out_size, void* d_ws, size_t ws_size,
                              hipStream_t stream)
{
    (void)in_sizes; (void)n_in; (void)out_size; (void)ws_size;

    const float* qin  = (const float*)d_in[0];
    const float* kin  = (const float*)d_in[1];
    const float* vin  = (const float*)d_in[2];
    const float* pos  = (const float*)d_in[3];
    const int*   mask = (const int*)d_in[4];
    const float* Wq   = (const float*)d_in[5];
    const float* bq   = (const float*)d_in[6];
    const float* Wk   = (const float*)d_in[7];
    const float* bk   = (const float*)d_in[8];
    const float* Wv   = (const float*)d_in[9];
    const float* bv   = (const float*)d_in[10];
    const float* Wfc  = (const float*)d_in[11];
    const float* bfc  = (const float*)d_in[12];
    float* out = (float*)d_out;

    short* ws  = (short*)d_ws;
    short* Whi = ws;                                  // 4*65536 shorts
    short* Qw  = Whi + 4 * 65536;
    short* Kw  = Qw + (size_t)NTOK * HIDDIM;
    short* Vt  = Kw + (size_t)NTOK * HIDDIM;
    short* Xp  = Vt + (size_t)NTOK * HIDDIM;              // NSEG*NTOK*HIDDIM bf16
    float* Sp  = (float*)(Xp + (size_t)NSEG * NTOK * HIDDIM);  // NSEG*16*128*16 f32
    unsigned* Mb = (unsigned*)(Sp + (size_t)NSEG * 16 * 128 * 16);  // 128 u32

    prep_kernel<<<dim3(65536 / 256, 4), 256, 0, stream>>>(Wq, Wk, Wv, Wfc, mask, Whi, Mb);
    qkv_kernel<<<dim3(NTOK / 16, 3), 256, 0, stream>>>(
        qin, kin, vin, bq, bk, bv, Whi, Qw, Kw, Vt);
    attn_kernel<<<dim3(SEQ / 64, NBATCH * NHEADS, NSEG), 256, 0, stream>>>(
        Qw, Kw, Vt, pos, Mb, Xp, Sp);
    fc_kernel<<<dim3(NTOK / 16, 2), 256, 0, stream>>>(
        Xp, Sp, Whi, bfc, out);
}